// Round 2
// baseline (237.209 us; speedup 1.0000x reference)
//
#include <hip/hip_runtime.h>
#include <math.h>

#define WPB 4  // waves per block (block = 256 threads)

// Fused per-bit rotation: qubit n acts on global bit b = 9-n,
// theta_b = 0.5 * sum_{l,k} angles[l][n][k].  (Rz,Ry,Rx are all 2D rotations
// -> compose by angle addition; layers fuse because cnot_matrix is the
// identity permutation: the reference's row-swap loop visits each pair twice.)
//
// Data layout (held end-to-end, loads AND stores coalesced float4):
//   element i = 256*m + 4*lane + k   ->   v[4*m + k]
//   reg bits  : {0,1} = k, {8,9} = m     -> in-register butterflies
//   lane bits : global bits 2..7 = lane bits 0..5
//       bits 2..6 -> ds_swizzle XOR mode (masks 1,2,4,8,16), conflict-free
//       bit  7    -> permlane32_swap (VALU pipe, lane^32)
// No __shared__, no barriers, no explicit s_waitcnt drains: pure stream.

__global__ __launch_bounds__(256) void qel_swz(
    const float* __restrict__ x,
    const float* __restrict__ ang,   // [4][10][3]
    float* __restrict__ out,
    int rows)
{
    const int tid  = threadIdx.x;
    const int lane = tid & 63;

    float cb[10], sb[10];
#pragma unroll
    for (int n = 0; n < 10; ++n) {
        float t = 0.f;
#pragma unroll
        for (int l = 0; l < 4; ++l) {
            const float* a = ang + (l * 10 + n) * 3;
            t += a[0] + a[1] + a[2];
        }
        t *= 0.5f;
        sincosf(t, &sb[9 - n], &cb[9 - n]);
    }

    // Signed sine per lane for the 6 cross-lane stages.
    // Lane bit B handles global bit B+2.  Partner value p comes from lane^2^B:
    //   bit==0 (lo): v' = c*lo - s*hi  -> se = -s
    //   bit==1 (hi): v' = s*lo + c*hi  -> se = +s
    //   either way:  v' = fma(c, v, se*p)
    float se[6];
#pragma unroll
    for (int B = 0; B < 6; ++B)
        se[B] = ((lane >> B) & 1) ? sb[B + 2] : -sb[B + 2];

    const int waveId = blockIdx.x * WPB + (tid >> 6);
    const int nW     = gridDim.x * WPB;

// in-register butterfly on register-index bit P with rotation (CC,SS)
#define RSTAGE(P, CC, SS)                                        \
    do {                                                         \
        _Pragma("unroll")                                        \
        for (int q = 0; q < 16; ++q)                             \
            if ((q & (1 << (P))) == 0) {                         \
                const float lo = v[q], hi = v[q | (1 << (P))];   \
                v[q]              = (CC) * lo - (SS) * hi;       \
                v[q | (1 << (P))] = (SS) * lo + (CC) * hi;       \
            }                                                    \
    } while (0)

// cross-lane butterfly on lane bit B via ds_swizzle XOR mode (imm = xor<<10 | 0x1F)
#define XSTAGE(B, IMM)                                               \
    do {                                                             \
        float p[16];                                                 \
        _Pragma("unroll")                                            \
        for (int q = 0; q < 16; ++q)                                 \
            p[q] = __int_as_float(__builtin_amdgcn_ds_swizzle(       \
                       __float_as_int(v[q]), (IMM)));                \
        _Pragma("unroll")                                            \
        for (int q = 0; q < 16; ++q)                                 \
            v[q] = fmaf(cb[(B) + 2], v[q], se[B] * p[q]);            \
    } while (0)

    for (int row = waveId; row < rows; row += nW) {
        const float* xr = x   + (size_t)row * 1024;
        float*       yr = out + (size_t)row * 1024;
        float v[16];

#pragma unroll
        for (int m = 0; m < 4; ++m) {
            const float4 t4 = *(const float4*)(xr + 256 * m + 4 * lane);
            v[4*m+0] = t4.x; v[4*m+1] = t4.y; v[4*m+2] = t4.z; v[4*m+3] = t4.w;
        }

        // global bits 0,1 (k) and 8,9 (m): in-register
        RSTAGE(0, cb[0], sb[0]);
        RSTAGE(1, cb[1], sb[1]);
        RSTAGE(2, cb[8], sb[8]);
        RSTAGE(3, cb[9], sb[9]);

        // global bits 2..6: lane bits 0..4 via ds_swizzle xor
        XSTAGE(0, 0x041F);   // xor 1
        XSTAGE(1, 0x081F);   // xor 2
        XSTAGE(2, 0x101F);   // xor 4
        XSTAGE(3, 0x201F);   // xor 8
        XSTAGE(4, 0x401F);   // xor 16

        // global bit 7: lane bit 5 (xor 32) -> permlane32_swap on the VALU
        // pipe (keeps the shared per-CU DS pipe free); shfl fallback.
        {
            float p[16];
#pragma unroll
            for (int q = 0; q < 16; ++q) {
#if defined(__has_builtin) && __has_builtin(__builtin_amdgcn_permlane32_swap)
                const int a_ = __float_as_int(v[q]);
                auto r_ = __builtin_amdgcn_permlane32_swap(a_, a_, false, false);
                // returned vdst: hi lanes hold partner's value (from lanes 0-31);
                // returned vsrc: lo lanes hold partner's value (from lanes 32-63).
                p[q] = __int_as_float((lane & 32) ? r_[0] : r_[1]);
#else
                p[q] = __shfl_xor(v[q], 32, 64);
#endif
            }
#pragma unroll
            for (int q = 0; q < 16; ++q)
                v[q] = fmaf(cb[7], v[q], se[5] * p[q]);
        }

#pragma unroll
        for (int m = 0; m < 4; ++m) {
            const float4 t4 = make_float4(v[4*m+0], v[4*m+1], v[4*m+2], v[4*m+3]);
            *(float4*)(yr + 256 * m + 4 * lane) = t4;
        }
    }
#undef RSTAGE
#undef XSTAGE
}

extern "C" void kernel_launch(void* const* d_in, const int* in_sizes, int n_in,
                              void* d_out, int out_size, void* d_ws, size_t ws_size,
                              hipStream_t stream) {
    const float* x   = (const float*)d_in[0];
    const float* ang = (const float*)d_in[1];
    // d_in[2] (cnot_matrix) is provably the identity permutation -> unused.
    float* out = (float*)d_out;
    const int rows = in_sizes[0] / 1024;   // 32768
    int blocks = (rows + WPB - 1) / WPB;
    if (blocks > 2048) blocks = 2048;      // grid-stride, ~8 blocks/CU
    qel_swz<<<blocks, 256, 0, stream>>>(x, ang, out, rows);
}